// Round 12
// baseline (75.789 us; speedup 1.0000x reference)
//
#include <hip/hip_runtime.h>

// LiftSplatShoot: out(B,N,3+C,H,W,D) = concat(world, feats_broadcast)
// B=4 N=6 C=80 H=16 W=44 D=59 -> 82,739,712 fp32 (~331 MB). Write-bound.
// Round 12: r11 with ONE change — feature blocks own CONTIGUOUS chunk
// ranges (sequential ~160KB/block write streams, DRAM-row friendly)
// instead of 8MB-jump grid-stride. 77,880 wave-chunks = 816x40 + 1160x39
// over 1976 blocks; world blocks (72) unchanged; grid = 2048 exact fit.

#define BB 4
#define NN 6
#define CC 80
#define HH 16
#define WW 44
#define DD 59
#define BN (BB*NN)        // 24
#define PP (HH*WW)        // 704
#define CHO (CC+3)        // 83
#define DSTEP (0.9f/58.f)
#define Q4S 10384u        // float4s per slab (41536/4)
#define NFS 1920u         // feature slabs (24*80)
#define NFF4 (NFS*Q4S)    // feature float4s = 19,937,280 = 77,880 * 256
#define WBLK 72           // world blocks
#define FBLK 1976         // feature blocks (72+1976 = 2048 = 8/CU exact)

typedef float fx4 __attribute__((ext_vector_type(4)));
typedef unsigned int uint;

__device__ inline float waveMax(float v) {
#pragma unroll
    for (int o = 32; o; o >>= 1) v = fmaxf(v, __shfl_xor(v, o));
    return v;
}
__device__ inline float waveSum(float v) {
#pragma unroll
    for (int o = 32; o; o >>= 1) v += __shfl_xor(v, o);
    return v;
}

__global__ __launch_bounds__(256) void lss_fused(const float* __restrict__ feats,
                                                 const float* __restrict__ intr,
                                                 const float* __restrict__ extr,
                                                 float* __restrict__ out) {
    const int blk = blockIdx.x;
    const int tid = threadIdx.x;

    __shared__ float sf[PP];
    __shared__ float vw[PP + 1];
    __shared__ float sred[4];
    __shared__ float sbc[2];

    if (blk < WBLK) {
        // ---------------- world slab: bn = blk/3, ch = blk%3 ----------------
        const int bn = blk / 3;
        const int ch = blk - 3 * bn;

        // softmax of channel 79 into sf
        const float* f = feats + ((size_t)bn * CC + (CC - 1)) * PP;
        float m = -1e30f;
        for (int p = tid; p < PP; p += 256) { float v = f[p]; sf[p] = v; m = fmaxf(m, v); }
        m = waveMax(m);
        if ((tid & 63) == 0) sred[tid >> 6] = m;
        __syncthreads();
        if (tid == 0) sbc[0] = fmaxf(fmaxf(sred[0], sred[1]), fmaxf(sred[2], sred[3]));
        __syncthreads();
        const float mm = sbc[0];
        float s = 0.f;
        for (int p = tid; p < PP; p += 256) { float e = expf(sf[p] - mm); sf[p] = e; s += e; }
        s = waveSum(s);
        if ((tid & 63) == 0) sred[tid >> 6] = s;
        __syncthreads();
        if (tid == 0) sbc[1] = sred[0] + sred[1] + sred[2] + sred[3];
        __syncthreads();
        const float inv = 1.0f / sbc[1];

        // row ch of M = R*K^-1 (uniform)
        const float* K = intr + bn * 16;
        float a = K[0], b = K[1], c = K[2];
        float d = K[4], e = K[5], ff = K[6];
        float g = K[8], h9 = K[9], i9 = K[10];
        float det = a * (e * i9 - ff * h9) - b * (d * i9 - ff * g) + c * (d * h9 - e * g);
        float id = 1.0f / det;
        float kinv[9] = {
            (e * i9 - ff * h9) * id, (c * h9 - b * i9) * id, (b * ff - c * e) * id,
            (ff * g - d * i9) * id,  (a * i9 - c * g) * id,  (c * d - a * ff) * id,
            (d * h9 - e * g) * id,   (b * g - a * h9) * id,  (a * e - b * d) * id
        };
        const float* E = extr + bn * 16;
        float M0 = E[ch * 4 + 0] * kinv[0] + E[ch * 4 + 1] * kinv[3] + E[ch * 4 + 2] * kinv[6];
        float M1 = E[ch * 4 + 0] * kinv[1] + E[ch * 4 + 1] * kinv[4] + E[ch * 4 + 2] * kinv[7];
        float M2 = E[ch * 4 + 0] * kinv[2] + E[ch * 4 + 1] * kinv[5] + E[ch * 4 + 2] * kinv[8];
        const float T = E[ch * 4 + 3];

        for (int p = tid; p < PP; p += 256) {
            int hl = p / WW;
            int w  = p - hl * WW;
            float ray = M0 * (float)w + M1 * (float)hl + M2;
            vw[p] = ray * sf[p] * inv;
        }
        if (tid == 0) vw[PP] = 0.f;
        __syncthreads();

        // write the slab: out float4s [s*Q4S, (s+1)*Q4S)
        const uint s0 = (uint)(bn * CHO + ch) * Q4S;
        for (uint q = tid; q < Q4S; q += 256u) {
            uint c4 = q << 2;
            uint p  = c4 / 59u;
            uint d0 = c4 - 59u * p;
            uint kc = 59u - d0;              // first k using p+1 (>=4 if none)
            uint cw = (kc < 4u) ? 1u : 0u;
            float vA = vw[p];
            float vB = vw[p + cw];
            fx4 r;
#pragma unroll
            for (int k = 0; k < 4; ++k) {
                bool cr = ((uint)k >= kc);
                float val = cr ? vB : vA;
                uint dk = d0 + (uint)k - (cr ? 59u : 0u);
                r[k] = val * (0.1f + (float)dk * DSTEP) + T;
            }
            ((fx4*)out)[s0 + q] = r;
        }
    } else {
        // ---- feature slabs: contiguous chunk range per block (sequential) ----
        // 77,880 wave-chunks of 256 float4s; block b2 gets 40 (b2<816) or 39.
        const uint b2    = (uint)(blk - WBLK);
        const uint ext   = (b2 < 816u) ? b2 : 816u;
        const uint start = b2 * 39u + ext;
        const uint cnt   = 39u + ((b2 < 816u) ? 1u : 0u);

        for (uint it = 0; it < cnt; ++it) {
            uint g  = (start + it) * 256u + (uint)tid;   // float4 index, dense
            uint fs = g / Q4S;              // feature slab [0,1920)
            uint r4 = g - fs * Q4S;         // float4 within slab
            uint c4 = r4 << 2;
            uint p  = c4 / 59u;
            uint d0 = c4 - 59u * p;
            uint bn = fs / 80u;
            uint chf = fs - 80u * bn;       // 0..79
            uint kc = 59u - d0;
            uint cw = (kc < 4u) ? 1u : 0u;

            const float* src = feats + ((size_t)bn * CC + chf) * PP;
            float vA = src[p];
            float vB = src[p + cw];
            fx4 r;
#pragma unroll
            for (int k = 0; k < 4; ++k) r[k] = ((uint)k >= kc) ? vB : vA;

            uint s = bn * (uint)CHO + 3u + chf;   // output slab index
            ((fx4*)out)[s * Q4S + r4] = r;
        }
    }
}

extern "C" void kernel_launch(void* const* d_in, const int* in_sizes, int n_in,
                              void* d_out, int out_size, void* d_ws, size_t ws_size,
                              hipStream_t stream) {
    const float* feats = (const float*)d_in[0];
    const float* intr  = (const float*)d_in[1];
    const float* extr  = (const float*)d_in[2];
    float* out = (float*)d_out;

    lss_fused<<<WBLK + FBLK, 256, 0, stream>>>(feats, intr, extr, out);
}